// Round 16
// baseline (675.180 us; speedup 1.0000x reference)
//
#include <hip/hip_runtime.h>
#include <hip/hip_bf16.h>

#define B_  8
#define C_  128
#define M_  65536     // 256*256
#define EPSV 2e-05f

typedef __attribute__((ext_vector_type(8))) short bf16x8;
typedef __attribute__((ext_vector_type(4))) float f32x4;

#define MFMA(a, b, c) __builtin_amdgcn_mfma_f32_16x16x32_bf16((a), (b), (c), 0, 0, 0)

__device__ __forceinline__ short f2b(float f) {
    unsigned u = __float_as_uint(f);
    u = (u + 0x7FFFu + ((u >> 16) & 1u)) >> 16;
    return (short)u;
}

// byte offset of (row px, channel c) in a 256B-pitch swizzled bf16 tile
__device__ __forceinline__ int swz(int px, int c) {
    return px * 256 + ((((c >> 3) ^ (px & 15)) << 4) | ((c & 7) << 1));
}

// rotated-row LDS address for f32 matrix: element (i,k) -> conflict-free dots
__device__ __forceinline__ int rot(int i, int k) {
    return i * 128 + ((((k >> 2) + i) & 31) << 2) + (k & 3);
}

// ---------------- weight prepack:  Wp[rs][o][c] = W[o][c][r][s]  (bf16) -----
__global__ __launch_bounds__(256) void k_prep(const float* W1, const float* W2,
                                              short* wp1, short* wp2) {
    int idx = blockIdx.x * 256 + threadIdx.x;
    if (idx < 9 * 128 * 128) {
        int c = idx & 127, o = (idx >> 7) & 127, rs = idx >> 14;
        wp1[idx] = f2b(W1[(o * 128 + c) * 9 + rs]);
    }
    idx -= 9 * 128 * 128;
    if (idx >= 0 && idx < 9 * 256 * 128) {
        int c = idx & 127, o = (idx >> 7) & 255, rs = idx >> 15;
        wp2[idx] = f2b(W2[(o * 128 + c) * 9 + rs]);
    }
}

// ---------------- Gram + channel sums (ONE input per launch) ---------------
// grid: 256 blocks = 32 k-chunks x 8 b. Launched twice: styl (xt=null) then
// cont (xt=colored buffer): the cont pass ALSO emits the bf16-transposed
// image xt[b][px][c] from its LDS tile so k_transform never re-reads f32 cont.
__global__ __launch_bounds__(256, 2) void k_gram(const float* Xsrc, int which,
                                                 float* part, float* S, short* xt) {
    __shared__ short ls[128 * 264];         // 67.6 KB, pitch 264 bf16 (256+8 pad)
    int bx = blockIdx.x;
    int chunk = bx & 31, b = bx >> 5;
    const float* X = Xsrc + (size_t)b * C_ * M_ + chunk * 2048;
    int tid = threadIdx.x, lane = tid & 63, wid = tid >> 6;

    float sacc[32];
    #pragma unroll
    for (int p = 0; p < 32; ++p) sacc[p] = 0.f;
    f32x4 acc[2][8];
    for (int u = 0; u < 2; ++u)
        for (int j = 0; j < 8; ++j) acc[u][j] = (f32x4){0.f, 0.f, 0.f, 0.f};

    float4 pfA[8], pfB[8];

#define GLOAD(pf, g)                                                              \
    _Pragma("unroll")                                                             \
    for (int p = 0; p < 8; ++p)                                                   \
        pf[p] = *(const float4*)(X + (size_t)(wid + 4 * ((g) * 8 + p)) * M_ +     \
                                 kb + lane * 4);

#define GSTORE(pf, g)                                                             \
    _Pragma("unroll")                                                             \
    for (int p = 0; p < 8; ++p) {                                                 \
        int row = wid + 4 * ((g) * 8 + p);                                        \
        float4 v = pf[p];                                                         \
        sacc[(g) * 8 + p] += v.x + v.y + v.z + v.w;                               \
        union { __hip_bfloat162 h[2]; unsigned long long u; } pk;                 \
        pk.h[0] = __float22bfloat162_rn(make_float2(v.x, v.y));                   \
        pk.h[1] = __float22bfloat162_rn(make_float2(v.z, v.w));                   \
        *(unsigned long long*)(ls + row * 264 + lane * 4) = pk.u;                 \
    }

    for (int it = 0; it < 8; ++it) {
        int kb = it * 256;
        GLOAD(pfA, 0)
        GLOAD(pfB, 1)
        GSTORE(pfA, 0)
        GLOAD(pfA, 2)
        GSTORE(pfB, 1)
        GLOAD(pfB, 3)
        GSTORE(pfA, 2)
        GSTORE(pfB, 3)
        asm volatile("s_waitcnt lgkmcnt(0)" ::: "memory");
        __builtin_amdgcn_sched_barrier(0);
        __builtin_amdgcn_s_barrier();           // ls ready
        // ---- MFMA phase: 8 k-slices x 16 = 128 MFMAs per wave --------------
        for (int ks = 0; ks < 8; ++ks) {
            int co = ks * 32 + (lane >> 4) * 8;
            bf16x8 a[2], bbf[8];
            for (int u = 0; u < 2; ++u) {
                int row = (wid * 2 + u) * 16 + (lane & 15);
                a[u] = *(const bf16x8*)(ls + row * 264 + co);
            }
            for (int j = 0; j < 8; ++j) {
                int row = j * 16 + (lane & 15);
                bbf[j] = *(const bf16x8*)(ls + row * 264 + co);
            }
            for (int u = 0; u < 2; ++u)
                for (int j = 0; j < 8; ++j)
                    acc[u][j] = MFMA(a[u], bbf[j], acc[u][j]);
        }
        // ---- xt emit (cont pass only): transpose LDS tile -> NHWC bf16 -----
        if (xt) {
            int h = tid >> 7, p = tid & 127;
            int px0 = 2 * p;                // this thread: px0, px0+1, c in [h*64, h*64+64)
            short* xrow = xt + ((size_t)b * M_ + chunk * 2048 + it * 256 + px0) * 128 + h * 64;
            #pragma unroll
            for (int g8 = 0; g8 < 8; ++g8) {
                bf16x8 lo, hi;
                #pragma unroll
                for (int e = 0; e < 8; ++e) {
                    int c = h * 64 + g8 * 8 + e;
                    unsigned w = *(const unsigned*)(ls + c * 264 + px0);
                    lo[e] = (short)(w & 0xFFFF);
                    hi[e] = (short)(w >> 16);
                }
                *(bf16x8*)(xrow + g8 * 8) = lo;
                *(bf16x8*)(xrow + 128 + g8 * 8) = hi;
            }
        }
        __builtin_amdgcn_sched_barrier(0);
        __builtin_amdgcn_s_barrier();           // ls free for next store
    }
#undef GLOAD
#undef GSTORE
    // ---- channel sums: full-wave butterfly per slot (row = wid + 4*slot) ---
    float* Sp = S + ((size_t)which * 8 + b) * 128;
    #pragma unroll
    for (int p = 0; p < 32; ++p) {
        float s = sacc[p];
        s += __shfl_xor(s, 1); s += __shfl_xor(s, 2);
        s += __shfl_xor(s, 4); s += __shfl_xor(s, 8);
        s += __shfl_xor(s, 16); s += __shfl_xor(s, 32);
        if (lane == 0) atomicAdd(&Sp[wid + 4 * p], s);
    }
    // ---- partial Gram store ------------------------------------------------
    float* Pp = part + ((size_t)((which * 8 + b) * 32 + chunk)) * 16384;
    for (int u = 0; u < 2; ++u) {
        int rowb = (wid * 2 + u) * 16 + (lane >> 4) * 4;
        for (int j = 0; j < 8; ++j) {
            int col = j * 16 + (lane & 15);
            for (int e = 0; e < 4; ++e)
                Pp[(rowb + e) * 128 + col] = acc[u][j][e];
        }
    }
}

// ---------------- reduce partial Grams: G = sum over 32 chunks -------------
__global__ __launch_bounds__(256) void k_gsum(const float* part, float* G) {
    int idx = blockIdx.x * 256 + threadIdx.x;   // 16*16384 elems
    int m = idx >> 14, e = idx & 16383;
    const float* p = part + (size_t)m * 32 * 16384 + e;
    float s = 0.f;
    #pragma unroll
    for (int c = 0; c < 32; ++c) s += p[(size_t)c * 16384];
    G[idx] = s;
}

// ---------------- fused solver: chol(cov_c) || chol(cov_s), then trsm ------
// 8 blocks x 256 threads. LDS: A (Lc image) + Bm (Ls -> T image), rotated.
// threads 0-127: content matrix rows; 128-255: style matrix rows (lockstep).
__global__ __launch_bounds__(256) void k_solve(const float* G, const float* S,
                                               short* Tb, float* Vv) {
    __shared__ float A[16384];              // 64 KiB
    __shared__ float Bm[16384];             // 64 KiB
    __shared__ float muA[128], muB[128];
    int b = blockIdx.x;
    int tid = threadIdx.x;
    int half = tid >> 7, i = tid & 127;
    const float invM = 1.f / 65536.f;
    const float invM1 = 1.f / 65535.f;
    float* M = half ? Bm : A;
    float* mu = half ? muB : muA;
    const float* Gp = G + ((size_t)(half * 8 + b)) * 16384;
    const float* Sp = S + ((size_t)(half * 8 + b)) * 128;

    mu[i] = Sp[i] * invM;
    __syncthreads();

    // ---- stage cov = (G - M mu mu^T)/(M-1) + eps I, rotated layout --------
    {
        const float4* G4 = (const float4*)Gp;
        int c4 = i & 31;                    // float4 column index
        #pragma unroll 4
        for (int bt = 0; bt < 4; ++bt) {
            float4 gv[8];
            #pragma unroll
            for (int q = 0; q < 8; ++q) gv[q] = G4[i + 128 * (bt * 8 + q)];
            #pragma unroll
            for (int q = 0; q < 8; ++q) {
                int it = bt * 8 + q;
                int r = (i >> 5) + 4 * it;
                float mur = mu[r] * 65536.f;
                float4 mc = *(const float4*)&mu[c4 * 4];
                float4 g = gv[q], cv;
                cv.x = (g.x - mur * mc.x) * invM1;
                cv.y = (g.y - mur * mc.y) * invM1;
                cv.z = (g.z - mur * mc.z) * invM1;
                cv.w = (g.w - mur * mc.w) * invM1;
                int c0 = c4 * 4;
                if (r == c0 + 0) cv.x += EPSV;
                if (r == c0 + 1) cv.y += EPSV;
                if (r == c0 + 2) cv.z += EPSV;
                if (r == c0 + 3) cv.w += EPSV;
                *(float4*)(M + r * 128 + (((c4 + r) & 31) << 2)) = cv;
            }
        }
    }
    __syncthreads();

    // ---- blocked Cholesky (NB=32), both halves in lockstep ----------------
    #pragma unroll 1
    for (int bb = 0; bb < 4; ++bb) {
        const int jb0 = bb * 32, bend = jb0 + 32;
        float t[32], u[32], t0[32];
        #pragma unroll
        for (int g = 0; g < 8; ++g) {
            float4 v = *(const float4*)(M + i * 128 + ((((jb0 >> 2) + g + i) & 31) << 2));
            t0[g * 4 + 0] = v.x; t0[g * 4 + 1] = v.y;
            t0[g * 4 + 2] = v.z; t0[g * 4 + 3] = v.w;
        }
        #pragma unroll
        for (int jj = 0; jj < 32; ++jj) {
            const int j = jb0 + jj;
            float dot = 0.f;
            #pragma unroll
            for (int kk = 0; kk < jj; ++kk)
                dot += u[kk] * M[rot(j, jb0 + kk)];     // bcast published raws
            float raw = t0[jj] - dot;
            if (i >= j) M[rot(i, j)] = raw;
            __syncthreads();
            float pr = M[rot(j, j)];                    // bcast pivot raw
            float piv = sqrtf(pr);
            float rpj = 1.f / piv;
            float tv = (i > j) ? raw * rpj : (i == j ? piv : 0.f);
            t[jj] = tv;
            u[jj] = tv * rpj;
        }
        #pragma unroll
        for (int g = 0; g < 8; ++g) {
            float4 v = {t[g * 4], t[g * 4 + 1], t[g * 4 + 2], t[g * 4 + 3]};
            *(float4*)(M + i * 128 + ((((jb0 >> 2) + g + i) & 31) << 2)) =
                (i >= jb0) ? v : *(float4*)(M + i * 128 + ((((jb0 >> 2) + g + i) & 31) << 2));
        }
        __syncthreads();
        if (bb < 3) {
            if (i >= bend) {
                int jmax = (i & ~63) + 64;      // wave-uniform cap (junk upper ok)
                for (int j4 = bend; j4 < jmax; j4 += 4) {
                    float* rp_ = M + i * 128 + ((((j4 >> 2) + i) & 31) << 2);
                    float4 r = *(float4*)rp_;
                    #pragma unroll
                    for (int g = 0; g < 8; ++g) {
                        int kc = (jb0 >> 2) + g;
                        float4 c0 = *(const float4*)(M + (j4 + 0) * 128 + (((kc + j4 + 0) & 31) << 2));
                        float4 c1 = *(const float4*)(M + (j4 + 1) * 128 + (((kc + j4 + 1) & 31) << 2));
                        float4 c2 = *(const float4*)(M + (j4 + 2) * 128 + (((kc + j4 + 2) & 31) << 2));
                        float4 c3 = *(const float4*)(M + (j4 + 3) * 128 + (((kc + j4 + 3) & 31) << 2));
                        float ta = t[g * 4], tb = t[g * 4 + 1], tc = t[g * 4 + 2], td = t[g * 4 + 3];
                        r.x -= ta * c0.x + tb * c0.y + tc * c0.z + td * c0.w;
                        r.y -= ta * c1.x + tb * c1.y + tc * c1.z + td * c1.w;
                        r.z -= ta * c2.x + tb * c2.y + tc * c2.z + td * c2.w;
                        r.w -= ta * c3.x + tb * c3.y + tc * c3.z + td * c3.w;
                    }
                    *(float4*)rp_ = r;
                }
            }
            __syncthreads();
        }
    }
    __syncthreads();

    // ---- trsm prep: diag reciprocals + T diag -----------------------------
    float rdia = 0.f, tii = 0.f;
    if (half == 0) {
        rdia = 1.f / A[rot(i, i)];
        tii = Bm[rot(i, i)] * rdia;
    }
    __syncthreads();
    if (half == 0) {
        A[rot(i, i)] = rdia;
        Bm[rot(i, i)] = tii;
    }
    __syncthreads();

    // ---- trsm: T * Lc = Ls, blocked back-substitution ---------------------
    #pragma unroll 1
    for (int b2 = 3; b2 >= 0; --b2) {
        const int jb0 = b2 * 32, bend = jb0 + 32;
        if (half == 0) {
            float t[32], l0[32];
            #pragma unroll
            for (int g = 0; g < 8; ++g) {
                float4 v = *(const float4*)(Bm + i * 128 + ((((jb0 >> 2) + g + i) & 31) << 2));
                l0[g * 4 + 0] = v.x; l0[g * 4 + 1] = v.y;
                l0[g * 4 + 2] = v.z; l0[g * 4 + 3] = v.w;
            }
            #pragma unroll
            for (int jj = 31; jj >= 0; --jj) {
                const int j = jb0 + jj;
                float dot = (i < bend) ? tii * A[rot(i, j)] : 0.f;   // k = i term
                #pragma unroll
                for (int kk = jj + 1; kk < 32; ++kk) {
                    const int k = jb0 + kk;
                    dot += t[kk] * A[rot(k, j)];        // bcast Lc[k][j] (lower)
                }
                float val = (l0[jj] - dot) * A[rot(j, j)];   // * 1/Lc[j][j]
                t[jj] = (j < i) ? val : (j == i ? tii : 0.f);
            }
            #pragma unroll
            for (int g = 0; g < 8; ++g) {
                float4 v = {t[g * 4], t[g * 4 + 1], t[g * 4 + 2], t[g * 4 + 3]};
                *(float4*)(Bm + i * 128 + ((((jb0 >> 2) + g + i) & 31) << 2)) = v;
            }
        }
        __syncthreads();
        if (jb0 > 0) {
            if (i >= jb0) {                     // both halves co-process
                float th[32];
                #pragma unroll
                for (int g = 0; g < 8; ++g) {
                    float4 v = *(const float4*)(Bm + i * 128 + ((((jb0 >> 2) + g + i) & 31) << 2));
                    th[g * 4 + 0] = v.x; th[g * 4 + 1] = v.y;
                    th[g * 4 + 2] = v.z; th[g * 4 + 3] = v.w;
                }
                for (int j4 = half * 4; j4 < jb0; j4 += 8) {
                    float* rp = Bm + i * 128 + ((((j4 >> 2) + i) & 31) << 2);
                    float4 r = *(float4*)rp;
                    #pragma unroll
                    for (int kk = 0; kk < 32; ++kk) {
                        const int k = jb0 + kk;
                        float4 lc = *(const float4*)(A + k * 128 + ((((j4 >> 2) + k) & 31) << 2));
                        r.x -= th[kk] * lc.x; r.y -= th[kk] * lc.y;
                        r.z -= th[kk] * lc.z; r.w -= th[kk] * lc.w;
                    }
                    *(float4*)rp = r;
                }
            }
            __syncthreads();
        }
    }

    // ---- outputs: T (bf16, packed) and v = mu_s - T mu_c ------------------
    if (half == 0) {
        float vdot = 0.f;
        short* Tr = Tb + (size_t)b * 16384 + i * 128;
        for (int j4 = 0; j4 < 32; ++j4) {
            float4 tv = *(const float4*)(Bm + i * 128 + (((j4 + i) & 31) << 2));
            float4 mc = *(const float4*)&muA[j4 * 4];
            vdot += tv.x * mc.x + tv.y * mc.y + tv.z * mc.z + tv.w * mc.w;
            union { __hip_bfloat162 h[2]; unsigned long long u; } pk;
            pk.h[0] = __float22bfloat162_rn(make_float2(tv.x, tv.y));
            pk.h[1] = __float22bfloat162_rn(make_float2(tv.z, tv.w));
            *(unsigned long long*)(Tr + j4 * 4) = pk.u;
        }
        Vv[b * 128 + i] = muB[i] - vdot;
    }
}

// ---------------- colored = T x + v, IN-PLACE on xt (NHWC bf16) ------------
// grid: 4096 = 8 b x 512 tiles of 128 pixels ; 256 threads
__global__ __launch_bounds__(256) void k_transform(short* xt, const short* Tb,
                                                   const float* Vv) {
    __shared__ short ls[16384];             // 128 px x 256B swizzled
    char* lsb = (char*)ls;
    int bx = blockIdx.x;
    int b = bx >> 9, p0 = (bx & 511) << 7;
    int tid = threadIdx.x, lane = tid & 63, wid = tid >> 6;

    {   // stage: coalesced 16B loads from xt NHWC bf16 (no conversion)
        int prow = tid >> 1, hh = (tid & 1) * 64;
        const short* src = xt + ((size_t)b * M_ + p0 + prow) * 128 + hh;
        #pragma unroll
        for (int g8 = 0; g8 < 8; ++g8) {
            bf16x8 v = *(const bf16x8*)(src + g8 * 8);
            *(bf16x8*)(lsb + swz(prow, hh + g8 * 8)) = v;
        }
    }
    __syncthreads();
    f32x4 acc[8][2];
    for (int pg = 0; pg < 8; ++pg)
        for (int u = 0; u < 2; ++u) acc[pg][u] = (f32x4){0.f, 0.f, 0.f, 0.f};
    const short* Tbase = Tb + (size_t)b * 16384;
    for (int kc = 0; kc < 4; ++kc) {
        int co = kc * 32 + (lane >> 4) * 8;
        bf16x8 bfr[2], afr[8];
        for (int u = 0; u < 2; ++u) {
            int chn = (wid * 2 + u) * 16 + (lane & 15);
            bfr[u] = *(const bf16x8*)(Tbase + chn * 128 + co);
        }
        for (int pg = 0; pg < 8; ++pg) {
            int px = pg * 16 + (lane & 15);
            afr[pg] = *(const bf16x8*)(lsb + swz(px, co));
        }
        for (int pg = 0; pg < 8; ++pg)
            for (int u = 0; u < 2; ++u)
                acc[pg][u] = MFMA(afr[pg], bfr[u], acc[pg][u]);
    }
    __syncthreads();
    for (int u = 0; u < 2; ++u) {
        int chn = (wid * 2 + u) * 16 + (lane & 15);
        float vv = Vv[b * 128 + chn];
        for (int pg = 0; pg < 8; ++pg)
            for (int e = 0; e < 4; ++e) {
                int px = pg * 16 + (lane >> 4) * 4 + e;
                *(short*)(lsb + swz(px, chn)) = f2b(acc[pg][u][e] + vv);
            }
    }
    __syncthreads();
    short* dst = xt + ((size_t)b * M_ + p0) * 128;      // in-place
    for (int it = 0; it < 8; ++it) {
        int gid = tid + it * 256;
        int px = gid >> 4, gr = gid & 15;
        bf16x8 v = *(const bf16x8*)(lsb + px * 256 + ((gr ^ (px & 15)) << 4));
        *(bf16x8*)(dst + (size_t)px * 128 + gr * 8) = v;
    }
}

// ---------------- conv1: 3x3 stride2 reflect-pad, relu -> NHWC bf16 --------
__global__ __launch_bounds__(256) void k_conv1(const short* colored, const short* wp1,
                                               const float* b1, short* out1) {
    __shared__ short ls[130 * 128];
    char* lsb = (char*)ls;
    int x0 = blockIdx.x * 64, y = blockIdx.y, b = blockIdx.z;
    int tid = threadIdx.x, lane = tid & 63, wid = tid >> 6;

    f32x4 acc[4][2];
    for (int pg = 0; pg < 4; ++pg)
        for (int u = 0; u < 2; ++u) acc[pg][u] = (f32x4){0.f, 0.f, 0.f, 0.f};

    for (int r = 0; r < 3; ++r) {
        int grow = 2 * y - 1 + r;
        if (grow < 0) grow = -grow;
        __syncthreads();
        const short* src = colored + ((size_t)b * M_ + grow * 256) * 128;
        for (int it = 0; it < 9; ++it) {
            int gid = tid + it * 256;
            if (gid < 130 * 16) {
                int L = gid >> 4, gr = gid & 15;
                int gcol = 2 * x0 - 1 + L;
                if (gcol < 0) gcol = -gcol;
                else if (gcol > 255) gcol = 510 - gcol;
                bf16x8 v = *(const bf16x8*)(src + (size_t)gcol * 128 + gr * 8);
                *(bf16x8*)(lsb + L * 256 + ((gr ^ (L & 15)) << 4)) = v;
            }
        }
        __syncthreads();
        for (int s = 0; s < 3; ++s)
            for (int kc = 0; kc < 4; ++kc) {
                int co = kc * 32 + (lane >> 4) * 8;
                bf16x8 afr[4], bfr[2];
                for (int pg = 0; pg < 4; ++pg) {
                    int L = (pg * 16 + (lane & 15)) * 2 + s;
                    afr[pg] = *(const bf16x8*)(lsb + swz(L, co));
                }
                const short* wb = wp1 + (r * 3 + s) * 128 * 128;
                for (int u = 0; u < 2; ++u) {
                    int o = (wid * 2 + u) * 16 + (lane & 15);
                    bfr[u] = *(const bf16x8*)(wb + o * 128 + co);
                }
                for (int pg = 0; pg < 4; ++pg)
                    for (int u = 0; u < 2; ++u)
                        acc[pg][u] = MFMA(afr[pg], bfr[u], acc[pg][u]);
            }
    }
    __syncthreads();
    for (int u = 0; u < 2; ++u) {
        int o = (wid * 2 + u) * 16 + (lane & 15);
        float bias = b1[o];
        for (int pg = 0; pg < 4; ++pg)
            for (int e = 0; e < 4; ++e) {
                int px = pg * 16 + (lane >> 4) * 4 + e;
                float v = acc[pg][u][e] + bias;
                v = v > 0.f ? v : 0.f;
                *(short*)(lsb + swz(px, o)) = f2b(v);
            }
    }
    __syncthreads();
    short* dst = out1 + ((size_t)b * 16384 + y * 128 + x0) * 128;
    for (int it = 0; it < 4; ++it) {
        int gid = tid + it * 256;
        int px = gid >> 4, gr = gid & 15;
        bf16x8 v = *(const bf16x8*)(lsb + px * 256 + ((gr ^ (px & 15)) << 4));
        *(bf16x8*)(dst + (size_t)px * 128 + gr * 8) = v;
    }
}

// ---------------- conv2: 3x3 stride1 reflect-pad -> NCHW f32 (d_out) -------
// grid: (128, 8) ; 256 threads ; FULL-WIDTH tile = 128 px x 256 o
__global__ __launch_bounds__(256) void k_conv2(const short* out1, const short* wp2,
                                               const float* b2, float* outp) {
    __shared__ short ls[130 * 128];
    char* lsb = (char*)ls;
    int y = blockIdx.x, b = blockIdx.y;
    int tid = threadIdx.x, lane = tid & 63, wid = tid >> 6;

    f32x4 acc[8][4];
    for (int pg = 0; pg < 8; ++pg)
        for (int u = 0; u < 4; ++u) acc[pg][u] = (f32x4){0.f, 0.f, 0.f, 0.f};

    for (int r = 0; r < 3; ++r) {
        int grow = y - 1 + r;
        if (grow < 0) grow = -grow;
        else if (grow > 127) grow = 254 - grow;
        __syncthreads();
        const short* src = out1 + ((size_t)b * 16384 + grow * 128) * 128;
        for (int it = 0; it < 9; ++it) {
            int gid = tid + it * 256;
            if (gid < 130 * 16) {
                int L = gid >> 4, gr = gid & 15;
                int gcol = L - 1;
                if (gcol < 0) gcol = -gcol;
                else if (gcol > 127) gcol = 254 - gcol;
                bf16x8 v = *(const bf16x8*)(src + (size_t)gcol * 128 + gr * 8);
                *(bf16x8*)(lsb + L * 256 + ((gr ^ (L & 15)) << 4)) = v;
            }
        }
        __syncthreads();
        for (int s = 0; s < 3; ++s)
            for (int kc = 0; kc < 4; ++kc) {
                int co = kc * 32 + (lane >> 4) * 8;
                bf16x8 afr[8], bfr[4];
                for (int pg = 0; pg < 8; ++pg) {
                    int L = pg * 16 + (lane & 15) + s;
                    afr[pg] = *(const bf16x8*)(lsb + swz(L, co));
                }
                const short* wb = wp2 + (r * 3 + s) * 256 * 128;
                for (int u = 0; u < 4; ++u) {
                    int o = (wid * 4 + u) * 16 + (lane & 15);
                    bfr[u] = *(const bf16x8*)(wb + o * 128 + co);
                }
                for (int pg = 0; pg < 8; ++pg)
                    for (int u = 0; u < 4; ++u)
                        acc[pg][u] = MFMA(afr[pg], bfr[u], acc[pg][u]);
            }
    }
    for (int u = 0; u < 4; ++u) {
        int o = (wid * 4 + u) * 16 + (lane & 15);
        float bias = b2[o];
        float* dst = outp + ((size_t)b * 256 + o) * 16384 + y * 128;
        for (int pg = 0; pg < 8; ++pg) {
            float4 v;
            v.x = acc[pg][u][0] + bias;
            v.y = acc[pg][u][1] + bias;
            v.z = acc[pg][u][2] + bias;
            v.w = acc[pg][u][3] + bias;
            *(float4*)(dst + pg * 16 + (lane >> 4) * 4) = v;
        }
    }
}

extern "C" void kernel_launch(void* const* d_in, const int* in_sizes, int n_in,
                              void* d_out, int out_size, void* d_ws, size_t ws_size,
                              hipStream_t stream) {
    const float* cont = (const float*)d_in[0];
    const float* styl = (const float*)d_in[1];
    const float* W1 = (const float*)d_in[2];
    const float* b1 = (const float*)d_in[3];
    const float* W2 = (const float*)d_in[4];
    const float* b2 = (const float*)d_in[5];
    float* outp = (float*)d_out;
    char* ws = (char*)d_ws;

    float* G       = (float*)(ws + 0x0);        // 16*128*128 f32 = 1 MiB
    float* S       = (float*)(ws + 0x100000);   // 2*8*128 f32
    short* Tb      = (short*)(ws + 0x110000);   // 8*128*128 bf16
    float* Vv      = (float*)(ws + 0x150000);   // 8*128 f32
    short* wp1     = (short*)(ws + 0x160000);   // 9*128*128 bf16
    short* wp2     = (short*)(ws + 0x1A8000);   // 9*256*128 bf16
    short* colored = (short*)(ws + 0x400000);   // 128 MiB: xt then colored (in-place)
    short* out1    = (short*)(ws + 0x8400000);  // 32 MiB NHWC
    float* part    = (float*)(ws + 0x8400000);  // 32 MiB (aliases out1; dead before conv1)

    hipMemsetAsync(S, 0, 0x2000, stream);       // zero S accumulator only
    k_prep<<<1728, 256, 0, stream>>>(W1, W2, wp1, wp2);
    // styl FIRST (no xt), cont SECOND (emits xt into colored buffer)
    k_gram<<<256, 256, 0, stream>>>(styl, 1, part, S, nullptr);
    k_gram<<<256, 256, 0, stream>>>(cont, 0, part, S, colored);
    k_gsum<<<1024, 256, 0, stream>>>(part, G);
    k_solve<<<8, 256, 0, stream>>>(G, S, Tb, Vv);
    k_transform<<<4096, 256, 0, stream>>>(colored, Tb, Vv);
    k_conv1<<<dim3(2, 128, 8), 256, 0, stream>>>(colored, wp1, b1, out1);
    k_conv2<<<dim3(128, 8), 256, 0, stream>>>(out1, wp2, b2, outp);
}

// Round 17
// 615.373 us; speedup vs baseline: 1.0972x; 1.0972x over previous
//
#include <hip/hip_runtime.h>
#include <hip/hip_bf16.h>

#define B_  8
#define C_  128
#define M_  65536     // 256*256
#define EPSV 2e-05f

typedef __attribute__((ext_vector_type(8))) short bf16x8;
typedef __attribute__((ext_vector_type(4))) float f32x4;

#define MFMA(a, b, c) __builtin_amdgcn_mfma_f32_16x16x32_bf16((a), (b), (c), 0, 0, 0)

__device__ __forceinline__ short f2b(float f) {
    unsigned u = __float_as_uint(f);
    u = (u + 0x7FFFu + ((u >> 16) & 1u)) >> 16;
    return (short)u;
}

// byte offset of (row px, channel c) in a 256B-pitch swizzled bf16 tile
__device__ __forceinline__ int swz(int px, int c) {
    return px * 256 + ((((c >> 3) ^ (px & 15)) << 4) | ((c & 7) << 1));
}

// rotated-row LDS address for f32 matrix: element (i,k) -> conflict-free dots
__device__ __forceinline__ int rot(int i, int k) {
    return i * 128 + ((((k >> 2) + i) & 31) << 2) + (k & 3);
}

// ---------------- weight prepack:  Wp[rs][o][c] = W[o][c][r][s]  (bf16) -----
__global__ __launch_bounds__(256) void k_prep(const float* W1, const float* W2,
                                              short* wp1, short* wp2) {
    int idx = blockIdx.x * 256 + threadIdx.x;
    if (idx < 9 * 128 * 128) {
        int c = idx & 127, o = (idx >> 7) & 127, rs = idx >> 14;
        wp1[idx] = f2b(W1[(o * 128 + c) * 9 + rs]);
    }
    idx -= 9 * 128 * 128;
    if (idx >= 0 && idx < 9 * 256 * 128) {
        int c = idx & 127, o = (idx >> 7) & 255, rs = idx >> 15;
        wp2[idx] = f2b(W2[(o * 128 + c) * 9 + rs]);
    }
}

// ---------------- Gram + channel sums (ONE input per launch) ---------------
// grid: 256 blocks = 32 k-chunks x 8 b ; launched twice: styl THEN cont so
// the Infinity Cache retains cont for k_transform's re-read (L3 ~256 MB).
__global__ __launch_bounds__(256, 2) void k_gram(const float* Xsrc, int which,
                                                 float* part, float* S) {
    __shared__ short ls[128 * 264];         // 67.6 KB, pitch 264 bf16 (256+8 pad)
    int bx = blockIdx.x;
    int chunk = bx & 31, b = bx >> 5;
    const float* X = Xsrc + (size_t)b * C_ * M_ + chunk * 2048;
    int tid = threadIdx.x, lane = tid & 63, wid = tid >> 6;

    float sacc[32];
    #pragma unroll
    for (int p = 0; p < 32; ++p) sacc[p] = 0.f;
    f32x4 acc[2][8];
    for (int u = 0; u < 2; ++u)
        for (int j = 0; j < 8; ++j) acc[u][j] = (f32x4){0.f, 0.f, 0.f, 0.f};

    float4 pfA[8], pfB[8];

#define GLOAD(pf, g)                                                              \
    _Pragma("unroll")                                                             \
    for (int p = 0; p < 8; ++p)                                                   \
        pf[p] = *(const float4*)(X + (size_t)(wid + 4 * ((g) * 8 + p)) * M_ +     \
                                 kb + lane * 4);

#define GSTORE(pf, g)                                                             \
    _Pragma("unroll")                                                             \
    for (int p = 0; p < 8; ++p) {                                                 \
        int row = wid + 4 * ((g) * 8 + p);                                        \
        float4 v = pf[p];                                                         \
        sacc[(g) * 8 + p] += v.x + v.y + v.z + v.w;                               \
        union { __hip_bfloat162 h[2]; unsigned long long u; } pk;                 \
        pk.h[0] = __float22bfloat162_rn(make_float2(v.x, v.y));                   \
        pk.h[1] = __float22bfloat162_rn(make_float2(v.z, v.w));                   \
        *(unsigned long long*)(ls + row * 264 + lane * 4) = pk.u;                 \
    }

    for (int it = 0; it < 8; ++it) {
        int kb = it * 256;
        GLOAD(pfA, 0)
        GLOAD(pfB, 1)
        GSTORE(pfA, 0)
        GLOAD(pfA, 2)
        GSTORE(pfB, 1)
        GLOAD(pfB, 3)
        GSTORE(pfA, 2)
        GSTORE(pfB, 3)
        asm volatile("s_waitcnt lgkmcnt(0)" ::: "memory");
        __builtin_amdgcn_sched_barrier(0);
        __builtin_amdgcn_s_barrier();           // ls ready
        // ---- MFMA phase: 8 k-slices x 16 = 128 MFMAs per wave --------------
        for (int ks = 0; ks < 8; ++ks) {
            int co = ks * 32 + (lane >> 4) * 8;
            bf16x8 a[2], bbf[8];
            for (int u = 0; u < 2; ++u) {
                int row = (wid * 2 + u) * 16 + (lane & 15);
                a[u] = *(const bf16x8*)(ls + row * 264 + co);
            }
            for (int j = 0; j < 8; ++j) {
                int row = j * 16 + (lane & 15);
                bbf[j] = *(const bf16x8*)(ls + row * 264 + co);
            }
            for (int u = 0; u < 2; ++u)
                for (int j = 0; j < 8; ++j)
                    acc[u][j] = MFMA(a[u], bbf[j], acc[u][j]);
        }
        __builtin_amdgcn_sched_barrier(0);
        __builtin_amdgcn_s_barrier();           // ls free for next store
    }
#undef GLOAD
#undef GSTORE
    // ---- channel sums: full-wave butterfly per slot (row = wid + 4*slot) ---
    float* Sp = S + ((size_t)which * 8 + b) * 128;
    #pragma unroll
    for (int p = 0; p < 32; ++p) {
        float s = sacc[p];
        s += __shfl_xor(s, 1); s += __shfl_xor(s, 2);
        s += __shfl_xor(s, 4); s += __shfl_xor(s, 8);
        s += __shfl_xor(s, 16); s += __shfl_xor(s, 32);
        if (lane == 0) atomicAdd(&Sp[wid + 4 * p], s);
    }
    // ---- partial Gram store ------------------------------------------------
    float* Pp = part + ((size_t)((which * 8 + b) * 32 + chunk)) * 16384;
    for (int u = 0; u < 2; ++u) {
        int rowb = (wid * 2 + u) * 16 + (lane >> 4) * 4;
        for (int j = 0; j < 8; ++j) {
            int col = j * 16 + (lane & 15);
            for (int e = 0; e < 4; ++e)
                Pp[(rowb + e) * 128 + col] = acc[u][j][e];
        }
    }
}

// ---------------- reduce partial Grams: G = sum over 32 chunks -------------
__global__ __launch_bounds__(256) void k_gsum(const float* part, float* G) {
    int idx = blockIdx.x * 256 + threadIdx.x;   // 16*16384 elems
    int m = idx >> 14, e = idx & 16383;
    const float* p = part + (size_t)m * 32 * 16384 + e;
    float s = 0.f;
    #pragma unroll
    for (int c = 0; c < 32; ++c) s += p[(size_t)c * 16384];
    G[idx] = s;
}

// ---------------- fused solver: chol(cov_c) || chol(cov_s), then trsm ------
// 8 blocks x 256 threads. LDS: A (Lc image) + Bm (Ls -> T image), rotated.
// threads 0-127: content matrix rows; 128-255: style matrix rows (lockstep).
__global__ __launch_bounds__(256) void k_solve(const float* G, const float* S,
                                               short* Tb, float* Vv) {
    __shared__ float A[16384];              // 64 KiB
    __shared__ float Bm[16384];             // 64 KiB
    __shared__ float muA[128], muB[128];
    int b = blockIdx.x;
    int tid = threadIdx.x;
    int half = tid >> 7, i = tid & 127;
    const float invM = 1.f / 65536.f;
    const float invM1 = 1.f / 65535.f;
    float* M = half ? Bm : A;
    float* mu = half ? muB : muA;
    const float* Gp = G + ((size_t)(half * 8 + b)) * 16384;
    const float* Sp = S + ((size_t)(half * 8 + b)) * 128;

    mu[i] = Sp[i] * invM;
    __syncthreads();

    // ---- stage cov = (G - M mu mu^T)/(M-1) + eps I, rotated layout --------
    {
        const float4* G4 = (const float4*)Gp;
        int c4 = i & 31;                    // float4 column index
        #pragma unroll 4
        for (int bt = 0; bt < 4; ++bt) {
            float4 gv[8];
            #pragma unroll
            for (int q = 0; q < 8; ++q) gv[q] = G4[i + 128 * (bt * 8 + q)];
            #pragma unroll
            for (int q = 0; q < 8; ++q) {
                int it = bt * 8 + q;
                int r = (i >> 5) + 4 * it;
                float mur = mu[r] * 65536.f;
                float4 mc = *(const float4*)&mu[c4 * 4];
                float4 g = gv[q], cv;
                cv.x = (g.x - mur * mc.x) * invM1;
                cv.y = (g.y - mur * mc.y) * invM1;
                cv.z = (g.z - mur * mc.z) * invM1;
                cv.w = (g.w - mur * mc.w) * invM1;
                int c0 = c4 * 4;
                if (r == c0 + 0) cv.x += EPSV;
                if (r == c0 + 1) cv.y += EPSV;
                if (r == c0 + 2) cv.z += EPSV;
                if (r == c0 + 3) cv.w += EPSV;
                *(float4*)(M + r * 128 + (((c4 + r) & 31) << 2)) = cv;
            }
        }
    }
    __syncthreads();

    // ---- blocked Cholesky (NB=32), both halves in lockstep ----------------
    #pragma unroll 1
    for (int bb = 0; bb < 4; ++bb) {
        const int jb0 = bb * 32, bend = jb0 + 32;
        float t[32], u[32], t0[32];
        #pragma unroll
        for (int g = 0; g < 8; ++g) {
            float4 v = *(const float4*)(M + i * 128 + ((((jb0 >> 2) + g + i) & 31) << 2));
            t0[g * 4 + 0] = v.x; t0[g * 4 + 1] = v.y;
            t0[g * 4 + 2] = v.z; t0[g * 4 + 3] = v.w;
        }
        #pragma unroll
        for (int jj = 0; jj < 32; ++jj) {
            const int j = jb0 + jj;
            float dot = 0.f;
            #pragma unroll
            for (int kk = 0; kk < jj; ++kk)
                dot += u[kk] * M[rot(j, jb0 + kk)];     // bcast published raws
            float raw = t0[jj] - dot;
            if (i >= j) M[rot(i, j)] = raw;
            __syncthreads();
            float pr = M[rot(j, j)];                    // bcast pivot raw
            float piv = sqrtf(pr);
            float rpj = 1.f / piv;
            float tv = (i > j) ? raw * rpj : (i == j ? piv : 0.f);
            t[jj] = tv;
            u[jj] = tv * rpj;
        }
        #pragma unroll
        for (int g = 0; g < 8; ++g) {
            float4 v = {t[g * 4], t[g * 4 + 1], t[g * 4 + 2], t[g * 4 + 3]};
            *(float4*)(M + i * 128 + ((((jb0 >> 2) + g + i) & 31) << 2)) =
                (i >= jb0) ? v : *(float4*)(M + i * 128 + ((((jb0 >> 2) + g + i) & 31) << 2));
        }
        __syncthreads();
        if (bb < 3) {
            if (i >= bend) {
                int jmax = (i & ~63) + 64;      // wave-uniform cap (junk upper ok)
                for (int j4 = bend; j4 < jmax; j4 += 4) {
                    float* rp_ = M + i * 128 + ((((j4 >> 2) + i) & 31) << 2);
                    float4 r = *(float4*)rp_;
                    #pragma unroll
                    for (int g = 0; g < 8; ++g) {
                        int kc = (jb0 >> 2) + g;
                        float4 c0 = *(const float4*)(M + (j4 + 0) * 128 + (((kc + j4 + 0) & 31) << 2));
                        float4 c1 = *(const float4*)(M + (j4 + 1) * 128 + (((kc + j4 + 1) & 31) << 2));
                        float4 c2 = *(const float4*)(M + (j4 + 2) * 128 + (((kc + j4 + 2) & 31) << 2));
                        float4 c3 = *(const float4*)(M + (j4 + 3) * 128 + (((kc + j4 + 3) & 31) << 2));
                        float ta = t[g * 4], tb = t[g * 4 + 1], tc = t[g * 4 + 2], td = t[g * 4 + 3];
                        r.x -= ta * c0.x + tb * c0.y + tc * c0.z + td * c0.w;
                        r.y -= ta * c1.x + tb * c1.y + tc * c1.z + td * c1.w;
                        r.z -= ta * c2.x + tb * c2.y + tc * c2.z + td * c2.w;
                        r.w -= ta * c3.x + tb * c3.y + tc * c3.z + td * c3.w;
                    }
                    *(float4*)rp_ = r;
                }
            }
            __syncthreads();
        }
    }
    __syncthreads();

    // ---- trsm prep: diag reciprocals + T diag -----------------------------
    float rdia = 0.f, tii = 0.f;
    if (half == 0) {
        rdia = 1.f / A[rot(i, i)];
        tii = Bm[rot(i, i)] * rdia;
    }
    __syncthreads();
    if (half == 0) {
        A[rot(i, i)] = rdia;
        Bm[rot(i, i)] = tii;
    }
    __syncthreads();

    // ---- trsm: T * Lc = Ls, blocked back-substitution ---------------------
    #pragma unroll 1
    for (int b2 = 3; b2 >= 0; --b2) {
        const int jb0 = b2 * 32, bend = jb0 + 32;
        if (half == 0) {
            float t[32], l0[32];
            #pragma unroll
            for (int g = 0; g < 8; ++g) {
                float4 v = *(const float4*)(Bm + i * 128 + ((((jb0 >> 2) + g + i) & 31) << 2));
                l0[g * 4 + 0] = v.x; l0[g * 4 + 1] = v.y;
                l0[g * 4 + 2] = v.z; l0[g * 4 + 3] = v.w;
            }
            #pragma unroll
            for (int jj = 31; jj >= 0; --jj) {
                const int j = jb0 + jj;
                float dot = (i < bend) ? tii * A[rot(i, j)] : 0.f;   // k = i term
                #pragma unroll
                for (int kk = jj + 1; kk < 32; ++kk) {
                    const int k = jb0 + kk;
                    dot += t[kk] * A[rot(k, j)];        // bcast Lc[k][j] (lower)
                }
                float val = (l0[jj] - dot) * A[rot(j, j)];   // * 1/Lc[j][j]
                t[jj] = (j < i) ? val : (j == i ? tii : 0.f);
            }
            #pragma unroll
            for (int g = 0; g < 8; ++g) {
                float4 v = {t[g * 4], t[g * 4 + 1], t[g * 4 + 2], t[g * 4 + 3]};
                *(float4*)(Bm + i * 128 + ((((jb0 >> 2) + g + i) & 31) << 2)) = v;
            }
        }
        __syncthreads();
        if (jb0 > 0) {
            if (i >= jb0) {                     // both halves co-process
                float th[32];
                #pragma unroll
                for (int g = 0; g < 8; ++g) {
                    float4 v = *(const float4*)(Bm + i * 128 + ((((jb0 >> 2) + g + i) & 31) << 2));
                    th[g * 4 + 0] = v.x; th[g * 4 + 1] = v.y;
                    th[g * 4 + 2] = v.z; th[g * 4 + 3] = v.w;
                }
                for (int j4 = half * 4; j4 < jb0; j4 += 8) {
                    float* rp = Bm + i * 128 + ((((j4 >> 2) + i) & 31) << 2);
                    float4 r = *(float4*)rp;
                    #pragma unroll
                    for (int kk = 0; kk < 32; ++kk) {
                        const int k = jb0 + kk;
                        float4 lc = *(const float4*)(A + k * 128 + ((((j4 >> 2) + k) & 31) << 2));
                        r.x -= th[kk] * lc.x; r.y -= th[kk] * lc.y;
                        r.z -= th[kk] * lc.z; r.w -= th[kk] * lc.w;
                    }
                    *(float4*)rp = r;
                }
            }
            __syncthreads();
        }
    }

    // ---- outputs: T (bf16, packed) and v = mu_s - T mu_c ------------------
    if (half == 0) {
        float vdot = 0.f;
        short* Tr = Tb + (size_t)b * 16384 + i * 128;
        for (int j4 = 0; j4 < 32; ++j4) {
            float4 tv = *(const float4*)(Bm + i * 128 + (((j4 + i) & 31) << 2));
            float4 mc = *(const float4*)&muA[j4 * 4];
            vdot += tv.x * mc.x + tv.y * mc.y + tv.z * mc.z + tv.w * mc.w;
            union { __hip_bfloat162 h[2]; unsigned long long u; } pk;
            pk.h[0] = __float22bfloat162_rn(make_float2(tv.x, tv.y));
            pk.h[1] = __float22bfloat162_rn(make_float2(tv.z, tv.w));
            *(unsigned long long*)(Tr + j4 * 4) = pk.u;
        }
        Vv[b * 128 + i] = muB[i] - vdot;
    }
}

// ---------------- colored = T x + v  -> NHWC bf16 --------------------------
// grid: 4096 = 8 b x 512 tiles of 128 pixels ; 256 threads
__global__ __launch_bounds__(256) void k_transform(const float* cont, const short* Tb,
                                                   const float* Vv, short* colored) {
    __shared__ short ls[16384];             // 128 px x 256B swizzled
    char* lsb = (char*)ls;
    int bx = blockIdx.x;
    int b = bx >> 9, p0 = (bx & 511) << 7;
    int tid = threadIdx.x, lane = tid & 63, wid = tid >> 6;

    {   // stage + transpose f32 NCHW -> bf16 [px][c]
        int px = tid & 127, ch = tid >> 7;
        const float* Xp = cont + (size_t)b * C_ * M_ + p0 + px;
        for (int it = 0; it < 16; ++it) {
            int c0 = it * 8 + ch * 4;
            float x0 = Xp[(size_t)(c0 + 0) * M_];
            float x1 = Xp[(size_t)(c0 + 1) * M_];
            float x2 = Xp[(size_t)(c0 + 2) * M_];
            float x3 = Xp[(size_t)(c0 + 3) * M_];
            union { short s[4]; unsigned long long u; } pk;
            pk.s[0] = f2b(x0); pk.s[1] = f2b(x1); pk.s[2] = f2b(x2); pk.s[3] = f2b(x3);
            *(unsigned long long*)(lsb + swz(px, c0)) = pk.u;
        }
    }
    __syncthreads();
    f32x4 acc[8][2];
    for (int pg = 0; pg < 8; ++pg)
        for (int u = 0; u < 2; ++u) acc[pg][u] = (f32x4){0.f, 0.f, 0.f, 0.f};
    const short* Tbase = Tb + (size_t)b * 16384;
    for (int kc = 0; kc < 4; ++kc) {
        int co = kc * 32 + (lane >> 4) * 8;
        bf16x8 bfr[2], afr[8];
        for (int u = 0; u < 2; ++u) {
            int chn = (wid * 2 + u) * 16 + (lane & 15);
            bfr[u] = *(const bf16x8*)(Tbase + chn * 128 + co);
        }
        for (int pg = 0; pg < 8; ++pg) {
            int px = pg * 16 + (lane & 15);
            afr[pg] = *(const bf16x8*)(lsb + swz(px, co));
        }
        for (int pg = 0; pg < 8; ++pg)
            for (int u = 0; u < 2; ++u)
                acc[pg][u] = MFMA(afr[pg], bfr[u], acc[pg][u]);
    }
    __syncthreads();
    for (int u = 0; u < 2; ++u) {
        int chn = (wid * 2 + u) * 16 + (lane & 15);
        float vv = Vv[b * 128 + chn];
        for (int pg = 0; pg < 8; ++pg)
            for (int e = 0; e < 4; ++e) {
                int px = pg * 16 + (lane >> 4) * 4 + e;
                *(short*)(lsb + swz(px, chn)) = f2b(acc[pg][u][e] + vv);
            }
    }
    __syncthreads();
    short* dst = colored + ((size_t)b * M_ + p0) * 128;
    for (int it = 0; it < 8; ++it) {
        int gid = tid + it * 256;
        int px = gid >> 4, gr = gid & 15;
        bf16x8 v = *(const bf16x8*)(lsb + px * 256 + ((gr ^ (px & 15)) << 4));
        *(bf16x8*)(dst + (size_t)px * 128 + gr * 8) = v;
    }
}

// ---------------- conv1: 3x3 stride2 reflect-pad, relu -> NHWC bf16 --------
// grid: (128, 8) ; 256 threads ; FULL-WIDTH tile = 128 out px x 128 o
__global__ __launch_bounds__(256) void k_conv1(const short* colored, const short* wp1,
                                               const float* b1, short* out1) {
    __shared__ short ls[258 * 128];         // 66 KB: 258 input cols staged
    char* lsb = (char*)ls;
    int y = blockIdx.x, b = blockIdx.y;
    int tid = threadIdx.x, lane = tid & 63, wid = tid >> 6;

    f32x4 acc[8][2];
    for (int pg = 0; pg < 8; ++pg)
        for (int u = 0; u < 2; ++u) acc[pg][u] = (f32x4){0.f, 0.f, 0.f, 0.f};

    for (int r = 0; r < 3; ++r) {
        int grow = 2 * y - 1 + r;
        if (grow < 0) grow = -grow;
        __syncthreads();
        const short* src = colored + ((size_t)b * M_ + grow * 256) * 128;
        for (int it = 0; it < 17; ++it) {
            int gid = tid + it * 256;
            if (gid < 258 * 16) {
                int L = gid >> 4, gr = gid & 15;
                int gcol = L - 1;
                if (gcol < 0) gcol = -gcol;
                else if (gcol > 255) gcol = 510 - gcol;
                bf16x8 v = *(const bf16x8*)(src + (size_t)gcol * 128 + gr * 8);
                *(bf16x8*)(lsb + L * 256 + ((gr ^ (L & 15)) << 4)) = v;
            }
        }
        __syncthreads();
        for (int s = 0; s < 3; ++s)
            for (int kc = 0; kc < 4; ++kc) {
                int co = kc * 32 + (lane >> 4) * 8;
                bf16x8 afr[8], bfr[2];
                for (int pg = 0; pg < 8; ++pg) {
                    int L = (pg * 16 + (lane & 15)) * 2 + s;
                    afr[pg] = *(const bf16x8*)(lsb + swz(L, co));
                }
                const short* wb = wp1 + (r * 3 + s) * 128 * 128;
                for (int u = 0; u < 2; ++u) {
                    int o = (wid * 2 + u) * 16 + (lane & 15);
                    bfr[u] = *(const bf16x8*)(wb + o * 128 + co);
                }
                for (int pg = 0; pg < 8; ++pg)
                    for (int u = 0; u < 2; ++u)
                        acc[pg][u] = MFMA(afr[pg], bfr[u], acc[pg][u]);
            }
    }
    __syncthreads();
    for (int u = 0; u < 2; ++u) {
        int o = (wid * 2 + u) * 16 + (lane & 15);
        float bias = b1[o];
        for (int pg = 0; pg < 8; ++pg)
            for (int e = 0; e < 4; ++e) {
                int px = pg * 16 + (lane >> 4) * 4 + e;
                float v = acc[pg][u][e] + bias;
                v = v > 0.f ? v : 0.f;
                *(short*)(lsb + swz(px, o)) = f2b(v);
            }
    }
    __syncthreads();
    short* dst = out1 + ((size_t)b * 16384 + y * 128) * 128;
    for (int it = 0; it < 8; ++it) {
        int gid = tid + it * 256;
        int px = gid >> 4, gr = gid & 15;
        bf16x8 v = *(const bf16x8*)(lsb + px * 256 + ((gr ^ (px & 15)) << 4));
        *(bf16x8*)(dst + (size_t)px * 128 + gr * 8) = v;
    }
}

// ---------------- conv2: 3x3 stride1 reflect-pad -> NCHW f32 (d_out) -------
// grid: (128, 8) ; 256 threads ; FULL-WIDTH tile = 128 px x 256 o
__global__ __launch_bounds__(256) void k_conv2(const short* out1, const short* wp2,
                                               const float* b2, float* outp) {
    __shared__ short ls[130 * 128];
    char* lsb = (char*)ls;
    int y = blockIdx.x, b = blockIdx.y;
    int tid = threadIdx.x, lane = tid & 63, wid = tid >> 6;

    f32x4 acc[8][4];
    for (int pg = 0; pg < 8; ++pg)
        for (int u = 0; u < 4; ++u) acc[pg][u] = (f32x4){0.f, 0.f, 0.f, 0.f};

    for (int r = 0; r < 3; ++r) {
        int grow = y - 1 + r;
        if (grow < 0) grow = -grow;
        else if (grow > 127) grow = 254 - grow;
        __syncthreads();
        const short* src = out1 + ((size_t)b * 16384 + grow * 128) * 128;
        for (int it = 0; it < 9; ++it) {
            int gid = tid + it * 256;
            if (gid < 130 * 16) {
                int L = gid >> 4, gr = gid & 15;
                int gcol = L - 1;
                if (gcol < 0) gcol = -gcol;
                else if (gcol > 127) gcol = 254 - gcol;
                bf16x8 v = *(const bf16x8*)(src + (size_t)gcol * 128 + gr * 8);
                *(bf16x8*)(lsb + L * 256 + ((gr ^ (L & 15)) << 4)) = v;
            }
        }
        __syncthreads();
        for (int s = 0; s < 3; ++s)
            for (int kc = 0; kc < 4; ++kc) {
                int co = kc * 32 + (lane >> 4) * 8;
                bf16x8 afr[8], bfr[4];
                for (int pg = 0; pg < 8; ++pg) {
                    int L = pg * 16 + (lane & 15) + s;
                    afr[pg] = *(const bf16x8*)(lsb + swz(L, co));
                }
                const short* wb = wp2 + (r * 3 + s) * 256 * 128;
                for (int u = 0; u < 4; ++u) {
                    int o = (wid * 4 + u) * 16 + (lane & 15);
                    bfr[u] = *(const bf16x8*)(wb + o * 128 + co);
                }
                for (int pg = 0; pg < 8; ++pg)
                    for (int u = 0; u < 4; ++u)
                        acc[pg][u] = MFMA(afr[pg], bfr[u], acc[pg][u]);
            }
    }
    for (int u = 0; u < 4; ++u) {
        int o = (wid * 4 + u) * 16 + (lane & 15);
        float bias = b2[o];
        float* dst = outp + ((size_t)b * 256 + o) * 16384 + y * 128;
        for (int pg = 0; pg < 8; ++pg) {
            float4 v;
            v.x = acc[pg][u][0] + bias;
            v.y = acc[pg][u][1] + bias;
            v.z = acc[pg][u][2] + bias;
            v.w = acc[pg][u][3] + bias;
            *(float4*)(dst + pg * 16 + (lane >> 4) * 4) = v;
        }
    }
}

extern "C" void kernel_launch(void* const* d_in, const int* in_sizes, int n_in,
                              void* d_out, int out_size, void* d_ws, size_t ws_size,
                              hipStream_t stream) {
    const float* cont = (const float*)d_in[0];
    const float* styl = (const float*)d_in[1];
    const float* W1 = (const float*)d_in[2];
    const float* b1 = (const float*)d_in[3];
    const float* W2 = (const float*)d_in[4];
    const float* b2 = (const float*)d_in[5];
    float* outp = (float*)d_out;
    char* ws = (char*)d_ws;

    float* G       = (float*)(ws + 0x0);        // 16*128*128 f32 = 1 MiB
    float* S       = (float*)(ws + 0x100000);   // 2*8*128 f32
    short* Tb      = (short*)(ws + 0x110000);   // 8*128*128 bf16
    float* Vv      = (float*)(ws + 0x150000);   // 8*128 f32
    short* wp1     = (short*)(ws + 0x160000);   // 9*128*128 bf16
    short* wp2     = (short*)(ws + 0x1A8000);   // 9*256*128 bf16
    short* colored = (short*)(ws + 0x400000);   // 8*65536*128 bf16 = 128 MiB NHWC
    float* part    = (float*)(ws + 0x400000);   // 512*16K f32 = 32 MiB (aliases colored)
    short* out1    = (short*)(ws + 0x8400000);  // 8*16384*128 bf16 = 32 MiB NHWC

    hipMemsetAsync(S, 0, 0x2000, stream);       // zero S accumulator only
    k_prep<<<1728, 256, 0, stream>>>(W1, W2, wp1, wp2);
    // styl FIRST, cont SECOND: Infinity Cache retains cont for k_transform
    k_gram<<<256, 256, 0, stream>>>(styl, 1, part, S);
    k_gram<<<256, 256, 0, stream>>>(cont, 0, part, S);
    k_gsum<<<1024, 256, 0, stream>>>(part, G);
    k_solve<<<8, 256, 0, stream>>>(G, S, Tb, Vv);
    k_transform<<<4096, 256, 0, stream>>>(cont, Tb, Vv, colored);
    k_conv1<<<dim3(128, 8), 256, 0, stream>>>(colored, wp1, b1, out1);
    k_conv2<<<dim3(128, 8), 256, 0, stream>>>(out1, wp2, b2, outp);
}

// Round 18
// 612.246 us; speedup vs baseline: 1.1028x; 1.0051x over previous
//
#include <hip/hip_runtime.h>
#include <hip/hip_bf16.h>

#define B_  8
#define C_  128
#define M_  65536     // 256*256
#define EPSV 2e-05f

typedef __attribute__((ext_vector_type(8))) short bf16x8;
typedef __attribute__((ext_vector_type(4))) float f32x4;

#define MFMA(a, b, c) __builtin_amdgcn_mfma_f32_16x16x32_bf16((a), (b), (c), 0, 0, 0)

__device__ __forceinline__ short f2b(float f) {
    unsigned u = __float_as_uint(f);
    u = (u + 0x7FFFu + ((u >> 16) & 1u)) >> 16;
    return (short)u;
}

// byte offset of (row px, channel c) in a 256B-pitch swizzled bf16 tile
__device__ __forceinline__ int swz(int px, int c) {
    return px * 256 + ((((c >> 3) ^ (px & 15)) << 4) | ((c & 7) << 1));
}

// rotated-row LDS address for f32 matrix: element (i,k) -> conflict-free dots
__device__ __forceinline__ int rot(int i, int k) {
    return i * 128 + ((((k >> 2) + i) & 31) << 2) + (k & 3);
}

// ---------------- weight prepack:  Wp[rs][o][c] = W[o][c][r][s]  (bf16) -----
__global__ __launch_bounds__(256) void k_prep(const float* W1, const float* W2,
                                              short* wp1, short* wp2) {
    int idx = blockIdx.x * 256 + threadIdx.x;
    if (idx < 9 * 128 * 128) {
        int c = idx & 127, o = (idx >> 7) & 127, rs = idx >> 14;
        wp1[idx] = f2b(W1[(o * 128 + c) * 9 + rs]);
    }
    idx -= 9 * 128 * 128;
    if (idx >= 0 && idx < 9 * 256 * 128) {
        int c = idx & 127, o = (idx >> 7) & 255, rs = idx >> 15;
        wp2[idx] = f2b(W2[(o * 128 + c) * 9 + rs]);
    }
}

// ---------------- Gram + channel sums (ONE input per launch) ---------------
// grid: 256 blocks = 32 k-chunks x 8 b ; launched twice: styl THEN cont so
// the Infinity Cache retains cont for k_transform's re-read (L3 ~256 MB).
__global__ __launch_bounds__(256, 2) void k_gram(const float* Xsrc, int which,
                                                 float* part, float* S) {
    __shared__ short ls[128 * 264];         // 67.6 KB, pitch 264 bf16 (256+8 pad)
    int bx = blockIdx.x;
    int chunk = bx & 31, b = bx >> 5;
    const float* X = Xsrc + (size_t)b * C_ * M_ + chunk * 2048;
    int tid = threadIdx.x, lane = tid & 63, wid = tid >> 6;

    float sacc[32];
    #pragma unroll
    for (int p = 0; p < 32; ++p) sacc[p] = 0.f;
    f32x4 acc[2][8];
    for (int u = 0; u < 2; ++u)
        for (int j = 0; j < 8; ++j) acc[u][j] = (f32x4){0.f, 0.f, 0.f, 0.f};

    float4 pfA[8], pfB[8];

#define GLOAD(pf, g)                                                              \
    _Pragma("unroll")                                                             \
    for (int p = 0; p < 8; ++p)                                                   \
        pf[p] = *(const float4*)(X + (size_t)(wid + 4 * ((g) * 8 + p)) * M_ +     \
                                 kb + lane * 4);

#define GSTORE(pf, g)                                                             \
    _Pragma("unroll")                                                             \
    for (int p = 0; p < 8; ++p) {                                                 \
        int row = wid + 4 * ((g) * 8 + p);                                        \
        float4 v = pf[p];                                                         \
        sacc[(g) * 8 + p] += v.x + v.y + v.z + v.w;                               \
        union { __hip_bfloat162 h[2]; unsigned long long u; } pk;                 \
        pk.h[0] = __float22bfloat162_rn(make_float2(v.x, v.y));                   \
        pk.h[1] = __float22bfloat162_rn(make_float2(v.z, v.w));                   \
        *(unsigned long long*)(ls + row * 264 + lane * 4) = pk.u;                 \
    }

    for (int it = 0; it < 8; ++it) {
        int kb = it * 256;
        GLOAD(pfA, 0)
        GLOAD(pfB, 1)
        GSTORE(pfA, 0)
        GLOAD(pfA, 2)
        GSTORE(pfB, 1)
        GLOAD(pfB, 3)
        GSTORE(pfA, 2)
        GSTORE(pfB, 3)
        asm volatile("s_waitcnt lgkmcnt(0)" ::: "memory");
        __builtin_amdgcn_sched_barrier(0);
        __builtin_amdgcn_s_barrier();           // ls ready
        // ---- MFMA phase: 8 k-slices x 16 = 128 MFMAs per wave --------------
        for (int ks = 0; ks < 8; ++ks) {
            int co = ks * 32 + (lane >> 4) * 8;
            bf16x8 a[2], bbf[8];
            for (int u = 0; u < 2; ++u) {
                int row = (wid * 2 + u) * 16 + (lane & 15);
                a[u] = *(const bf16x8*)(ls + row * 264 + co);
            }
            for (int j = 0; j < 8; ++j) {
                int row = j * 16 + (lane & 15);
                bbf[j] = *(const bf16x8*)(ls + row * 264 + co);
            }
            for (int u = 0; u < 2; ++u)
                for (int j = 0; j < 8; ++j)
                    acc[u][j] = MFMA(a[u], bbf[j], acc[u][j]);
        }
        __builtin_amdgcn_sched_barrier(0);
        __builtin_amdgcn_s_barrier();           // ls free for next store
    }
#undef GLOAD
#undef GSTORE
    // ---- channel sums: full-wave butterfly per slot (row = wid + 4*slot) ---
    float* Sp = S + ((size_t)which * 8 + b) * 128;
    #pragma unroll
    for (int p = 0; p < 32; ++p) {
        float s = sacc[p];
        s += __shfl_xor(s, 1); s += __shfl_xor(s, 2);
        s += __shfl_xor(s, 4); s += __shfl_xor(s, 8);
        s += __shfl_xor(s, 16); s += __shfl_xor(s, 32);
        if (lane == 0) atomicAdd(&Sp[wid + 4 * p], s);
    }
    // ---- partial Gram store ------------------------------------------------
    float* Pp = part + ((size_t)((which * 8 + b) * 32 + chunk)) * 16384;
    for (int u = 0; u < 2; ++u) {
        int rowb = (wid * 2 + u) * 16 + (lane >> 4) * 4;
        for (int j = 0; j < 8; ++j) {
            int col = j * 16 + (lane & 15);
            for (int e = 0; e < 4; ++e)
                Pp[(rowb + e) * 128 + col] = acc[u][j][e];
        }
    }
}

// ---------------- reduce partial Grams: G = sum over 32 chunks -------------
__global__ __launch_bounds__(256) void k_gsum(const float* part, float* G) {
    int idx = blockIdx.x * 256 + threadIdx.x;   // 16*16384 elems
    int m = idx >> 14, e = idx & 16383;
    const float* p = part + (size_t)m * 32 * 16384 + e;
    float s = 0.f;
    #pragma unroll
    for (int c = 0; c < 32; ++c) s += p[(size_t)c * 16384];
    G[idx] = s;
}

// ---------------- fused solver: chol(cov_c) || chol(cov_s), then trsm ------
// 8 blocks x 256 threads. LDS: A (Lc image) + Bm (Ls -> T image), rotated.
// threads 0-127: content matrix rows; 128-255: style matrix rows (lockstep).
__global__ __launch_bounds__(256) void k_solve(const float* G, const float* S,
                                               short* Tb, float* Vv) {
    __shared__ float A[16384];              // 64 KiB
    __shared__ float Bm[16384];             // 64 KiB
    __shared__ float muA[128], muB[128];
    int b = blockIdx.x;
    int tid = threadIdx.x;
    int half = tid >> 7, i = tid & 127;
    const float invM = 1.f / 65536.f;
    const float invM1 = 1.f / 65535.f;
    float* M = half ? Bm : A;
    float* mu = half ? muB : muA;
    const float* Gp = G + ((size_t)(half * 8 + b)) * 16384;
    const float* Sp = S + ((size_t)(half * 8 + b)) * 128;

    mu[i] = Sp[i] * invM;
    __syncthreads();

    // ---- stage cov = (G - M mu mu^T)/(M-1) + eps I, rotated layout --------
    {
        const float4* G4 = (const float4*)Gp;
        int c4 = i & 31;                    // float4 column index
        #pragma unroll 4
        for (int bt = 0; bt < 4; ++bt) {
            float4 gv[8];
            #pragma unroll
            for (int q = 0; q < 8; ++q) gv[q] = G4[i + 128 * (bt * 8 + q)];
            #pragma unroll
            for (int q = 0; q < 8; ++q) {
                int it = bt * 8 + q;
                int r = (i >> 5) + 4 * it;
                float mur = mu[r] * 65536.f;
                float4 mc = *(const float4*)&mu[c4 * 4];
                float4 g = gv[q], cv;
                cv.x = (g.x - mur * mc.x) * invM1;
                cv.y = (g.y - mur * mc.y) * invM1;
                cv.z = (g.z - mur * mc.z) * invM1;
                cv.w = (g.w - mur * mc.w) * invM1;
                int c0 = c4 * 4;
                if (r == c0 + 0) cv.x += EPSV;
                if (r == c0 + 1) cv.y += EPSV;
                if (r == c0 + 2) cv.z += EPSV;
                if (r == c0 + 3) cv.w += EPSV;
                *(float4*)(M + r * 128 + (((c4 + r) & 31) << 2)) = cv;
            }
        }
    }
    __syncthreads();

    // ---- blocked Cholesky (NB=32), both halves in lockstep ----------------
    #pragma unroll 1
    for (int bb = 0; bb < 4; ++bb) {
        const int jb0 = bb * 32, bend = jb0 + 32;
        float t[32], u[32], t0[32];
        #pragma unroll
        for (int g = 0; g < 8; ++g) {
            float4 v = *(const float4*)(M + i * 128 + ((((jb0 >> 2) + g + i) & 31) << 2));
            t0[g * 4 + 0] = v.x; t0[g * 4 + 1] = v.y;
            t0[g * 4 + 2] = v.z; t0[g * 4 + 3] = v.w;
        }
        #pragma unroll
        for (int jj = 0; jj < 32; ++jj) {
            const int j = jb0 + jj;
            float dot = 0.f;
            #pragma unroll
            for (int kk = 0; kk < jj; ++kk)
                dot += u[kk] * M[rot(j, jb0 + kk)];     // bcast published raws
            float raw = t0[jj] - dot;
            if (i >= j) M[rot(i, j)] = raw;
            __syncthreads();
            float pr = M[rot(j, j)];                    // bcast pivot raw
            float piv = sqrtf(pr);
            float rpj = 1.f / piv;
            float tv = (i > j) ? raw * rpj : (i == j ? piv : 0.f);
            t[jj] = tv;
            u[jj] = tv * rpj;
        }
        #pragma unroll
        for (int g = 0; g < 8; ++g) {
            float4 v = {t[g * 4], t[g * 4 + 1], t[g * 4 + 2], t[g * 4 + 3]};
            *(float4*)(M + i * 128 + ((((jb0 >> 2) + g + i) & 31) << 2)) =
                (i >= jb0) ? v : *(float4*)(M + i * 128 + ((((jb0 >> 2) + g + i) & 31) << 2));
        }
        __syncthreads();
        if (bb < 3) {
            if (i >= bend) {
                int jmax = (i & ~63) + 64;      // wave-uniform cap (junk upper ok)
                for (int j4 = bend; j4 < jmax; j4 += 4) {
                    float* rp_ = M + i * 128 + ((((j4 >> 2) + i) & 31) << 2);
                    float4 r = *(float4*)rp_;
                    #pragma unroll
                    for (int g = 0; g < 8; ++g) {
                        int kc = (jb0 >> 2) + g;
                        float4 c0 = *(const float4*)(M + (j4 + 0) * 128 + (((kc + j4 + 0) & 31) << 2));
                        float4 c1 = *(const float4*)(M + (j4 + 1) * 128 + (((kc + j4 + 1) & 31) << 2));
                        float4 c2 = *(const float4*)(M + (j4 + 2) * 128 + (((kc + j4 + 2) & 31) << 2));
                        float4 c3 = *(const float4*)(M + (j4 + 3) * 128 + (((kc + j4 + 3) & 31) << 2));
                        float ta = t[g * 4], tb = t[g * 4 + 1], tc = t[g * 4 + 2], td = t[g * 4 + 3];
                        r.x -= ta * c0.x + tb * c0.y + tc * c0.z + td * c0.w;
                        r.y -= ta * c1.x + tb * c1.y + tc * c1.z + td * c1.w;
                        r.z -= ta * c2.x + tb * c2.y + tc * c2.z + td * c2.w;
                        r.w -= ta * c3.x + tb * c3.y + tc * c3.z + td * c3.w;
                    }
                    *(float4*)rp_ = r;
                }
            }
            __syncthreads();
        }
    }
    __syncthreads();

    // ---- trsm prep: diag reciprocals + T diag -----------------------------
    float rdia = 0.f, tii = 0.f;
    if (half == 0) {
        rdia = 1.f / A[rot(i, i)];
        tii = Bm[rot(i, i)] * rdia;
    }
    __syncthreads();
    if (half == 0) {
        A[rot(i, i)] = rdia;
        Bm[rot(i, i)] = tii;
    }
    __syncthreads();

    // ---- trsm: T * Lc = Ls, blocked back-substitution ---------------------
    #pragma unroll 1
    for (int b2 = 3; b2 >= 0; --b2) {
        const int jb0 = b2 * 32, bend = jb0 + 32;
        if (half == 0) {
            float t[32], l0[32];
            #pragma unroll
            for (int g = 0; g < 8; ++g) {
                float4 v = *(const float4*)(Bm + i * 128 + ((((jb0 >> 2) + g + i) & 31) << 2));
                l0[g * 4 + 0] = v.x; l0[g * 4 + 1] = v.y;
                l0[g * 4 + 2] = v.z; l0[g * 4 + 3] = v.w;
            }
            #pragma unroll
            for (int jj = 31; jj >= 0; --jj) {
                const int j = jb0 + jj;
                float dot = (i < bend) ? tii * A[rot(i, j)] : 0.f;   // k = i term
                #pragma unroll
                for (int kk = jj + 1; kk < 32; ++kk) {
                    const int k = jb0 + kk;
                    dot += t[kk] * A[rot(k, j)];        // bcast Lc[k][j] (lower)
                }
                float val = (l0[jj] - dot) * A[rot(j, j)];   // * 1/Lc[j][j]
                t[jj] = (j < i) ? val : (j == i ? tii : 0.f);
            }
            #pragma unroll
            for (int g = 0; g < 8; ++g) {
                float4 v = {t[g * 4], t[g * 4 + 1], t[g * 4 + 2], t[g * 4 + 3]};
                *(float4*)(Bm + i * 128 + ((((jb0 >> 2) + g + i) & 31) << 2)) = v;
            }
        }
        __syncthreads();
        if (jb0 > 0) {
            if (i >= jb0) {                     // both halves co-process
                float th[32];
                #pragma unroll
                for (int g = 0; g < 8; ++g) {
                    float4 v = *(const float4*)(Bm + i * 128 + ((((jb0 >> 2) + g + i) & 31) << 2));
                    th[g * 4 + 0] = v.x; th[g * 4 + 1] = v.y;
                    th[g * 4 + 2] = v.z; th[g * 4 + 3] = v.w;
                }
                for (int j4 = half * 4; j4 < jb0; j4 += 8) {
                    float* rp = Bm + i * 128 + ((((j4 >> 2) + i) & 31) << 2);
                    float4 r = *(float4*)rp;
                    #pragma unroll
                    for (int kk = 0; kk < 32; ++kk) {
                        const int k = jb0 + kk;
                        float4 lc = *(const float4*)(A + k * 128 + ((((j4 >> 2) + k) & 31) << 2));
                        r.x -= th[kk] * lc.x; r.y -= th[kk] * lc.y;
                        r.z -= th[kk] * lc.z; r.w -= th[kk] * lc.w;
                    }
                    *(float4*)rp = r;
                }
            }
            __syncthreads();
        }
    }

    // ---- outputs: T (bf16, packed) and v = mu_s - T mu_c ------------------
    if (half == 0) {
        float vdot = 0.f;
        short* Tr = Tb + (size_t)b * 16384 + i * 128;
        for (int j4 = 0; j4 < 32; ++j4) {
            float4 tv = *(const float4*)(Bm + i * 128 + (((j4 + i) & 31) << 2));
            float4 mc = *(const float4*)&muA[j4 * 4];
            vdot += tv.x * mc.x + tv.y * mc.y + tv.z * mc.z + tv.w * mc.w;
            union { __hip_bfloat162 h[2]; unsigned long long u; } pk;
            pk.h[0] = __float22bfloat162_rn(make_float2(tv.x, tv.y));
            pk.h[1] = __float22bfloat162_rn(make_float2(tv.z, tv.w));
            *(unsigned long long*)(Tr + j4 * 4) = pk.u;
        }
        Vv[b * 128 + i] = muB[i] - vdot;
    }
}

// ---------------- colored = T x + v  -> NHWC bf16 --------------------------
// grid: 4096 = 8 b x 512 tiles of 128 pixels ; 256 threads
// REVERSED block->tile map: reads freshest-in-L3 cont chunks first (LRU win)
__global__ __launch_bounds__(256) void k_transform(const float* cont, const short* Tb,
                                                   const float* Vv, short* colored) {
    __shared__ short ls[16384];             // 128 px x 256B swizzled
    char* lsb = (char*)ls;
    int bx = 4095 - blockIdx.x;             // descending sweep vs ascending fill
    int b = bx >> 9, p0 = (bx & 511) << 7;
    int tid = threadIdx.x, lane = tid & 63, wid = tid >> 6;

    {   // stage + transpose f32 NCHW -> bf16 [px][c]
        int px = tid & 127, ch = tid >> 7;
        const float* Xp = cont + (size_t)b * C_ * M_ + p0 + px;
        for (int it = 0; it < 16; ++it) {
            int c0 = it * 8 + ch * 4;
            float x0 = Xp[(size_t)(c0 + 0) * M_];
            float x1 = Xp[(size_t)(c0 + 1) * M_];
            float x2 = Xp[(size_t)(c0 + 2) * M_];
            float x3 = Xp[(size_t)(c0 + 3) * M_];
            union { short s[4]; unsigned long long u; } pk;
            pk.s[0] = f2b(x0); pk.s[1] = f2b(x1); pk.s[2] = f2b(x2); pk.s[3] = f2b(x3);
            *(unsigned long long*)(lsb + swz(px, c0)) = pk.u;
        }
    }
    __syncthreads();
    f32x4 acc[8][2];
    for (int pg = 0; pg < 8; ++pg)
        for (int u = 0; u < 2; ++u) acc[pg][u] = (f32x4){0.f, 0.f, 0.f, 0.f};
    const short* Tbase = Tb + (size_t)b * 16384;
    for (int kc = 0; kc < 4; ++kc) {
        int co = kc * 32 + (lane >> 4) * 8;
        bf16x8 bfr[2], afr[8];
        for (int u = 0; u < 2; ++u) {
            int chn = (wid * 2 + u) * 16 + (lane & 15);
            bfr[u] = *(const bf16x8*)(Tbase + chn * 128 + co);
        }
        for (int pg = 0; pg < 8; ++pg) {
            int px = pg * 16 + (lane & 15);
            afr[pg] = *(const bf16x8*)(lsb + swz(px, co));
        }
        for (int pg = 0; pg < 8; ++pg)
            for (int u = 0; u < 2; ++u)
                acc[pg][u] = MFMA(afr[pg], bfr[u], acc[pg][u]);
    }
    __syncthreads();
    for (int u = 0; u < 2; ++u) {
        int chn = (wid * 2 + u) * 16 + (lane & 15);
        float vv = Vv[b * 128 + chn];
        for (int pg = 0; pg < 8; ++pg)
            for (int e = 0; e < 4; ++e) {
                int px = pg * 16 + (lane >> 4) * 4 + e;
                *(short*)(lsb + swz(px, chn)) = f2b(acc[pg][u][e] + vv);
            }
    }
    __syncthreads();
    short* dst = colored + ((size_t)b * M_ + p0) * 128;
    for (int it = 0; it < 8; ++it) {
        int gid = tid + it * 256;
        int px = gid >> 4, gr = gid & 15;
        bf16x8 v = *(const bf16x8*)(lsb + px * 256 + ((gr ^ (px & 15)) << 4));
        *(bf16x8*)(dst + (size_t)px * 128 + gr * 8) = v;
    }
}

// ---------------- conv1: 3x3 stride2 reflect-pad, relu -> NHWC bf16 --------
// grid: (128, 8) ; 256 threads ; FULL-WIDTH tile = 128 out px x 128 o
__global__ __launch_bounds__(256) void k_conv1(const short* colored, const short* wp1,
                                               const float* b1, short* out1) {
    __shared__ short ls[258 * 128];         // 66 KB: 258 input cols staged
    char* lsb = (char*)ls;
    int y = blockIdx.x, b = blockIdx.y;
    int tid = threadIdx.x, lane = tid & 63, wid = tid >> 6;

    f32x4 acc[8][2];
    for (int pg = 0; pg < 8; ++pg)
        for (int u = 0; u < 2; ++u) acc[pg][u] = (f32x4){0.f, 0.f, 0.f, 0.f};

    for (int r = 0; r < 3; ++r) {
        int grow = 2 * y - 1 + r;
        if (grow < 0) grow = -grow;
        __syncthreads();
        const short* src = colored + ((size_t)b * M_ + grow * 256) * 128;
        for (int it = 0; it < 17; ++it) {
            int gid = tid + it * 256;
            if (gid < 258 * 16) {
                int L = gid >> 4, gr = gid & 15;
                int gcol = L - 1;
                if (gcol < 0) gcol = -gcol;
                else if (gcol > 255) gcol = 510 - gcol;
                bf16x8 v = *(const bf16x8*)(src + (size_t)gcol * 128 + gr * 8);
                *(bf16x8*)(lsb + L * 256 + ((gr ^ (L & 15)) << 4)) = v;
            }
        }
        __syncthreads();
        for (int s = 0; s < 3; ++s)
            for (int kc = 0; kc < 4; ++kc) {
                int co = kc * 32 + (lane >> 4) * 8;
                bf16x8 afr[8], bfr[2];
                for (int pg = 0; pg < 8; ++pg) {
                    int L = (pg * 16 + (lane & 15)) * 2 + s;
                    afr[pg] = *(const bf16x8*)(lsb + swz(L, co));
                }
                const short* wb = wp1 + (r * 3 + s) * 128 * 128;
                for (int u = 0; u < 2; ++u) {
                    int o = (wid * 2 + u) * 16 + (lane & 15);
                    bfr[u] = *(const bf16x8*)(wb + o * 128 + co);
                }
                for (int pg = 0; pg < 8; ++pg)
                    for (int u = 0; u < 2; ++u)
                        acc[pg][u] = MFMA(afr[pg], bfr[u], acc[pg][u]);
            }
    }
    __syncthreads();
    for (int u = 0; u < 2; ++u) {
        int o = (wid * 2 + u) * 16 + (lane & 15);
        float bias = b1[o];
        for (int pg = 0; pg < 8; ++pg)
            for (int e = 0; e < 4; ++e) {
                int px = pg * 16 + (lane >> 4) * 4 + e;
                float v = acc[pg][u][e] + bias;
                v = v > 0.f ? v : 0.f;
                *(short*)(lsb + swz(px, o)) = f2b(v);
            }
    }
    __syncthreads();
    short* dst = out1 + ((size_t)b * 16384 + y * 128) * 128;
    for (int it = 0; it < 8; ++it) {
        int gid = tid + it * 256;
        int px = gid >> 4, gr = gid & 15;
        bf16x8 v = *(const bf16x8*)(lsb + px * 256 + ((gr ^ (px & 15)) << 4));
        *(bf16x8*)(dst + (size_t)px * 128 + gr * 8) = v;
    }
}

// ---------------- conv2: 3x3 stride1 reflect-pad -> NCHW f32 (d_out) -------
// grid: (128, 8) ; 256 threads ; FULL-WIDTH tile = 128 px x 256 o
__global__ __launch_bounds__(256) void k_conv2(const short* out1, const short* wp2,
                                               const float* b2, float* outp) {
    __shared__ short ls[130 * 128];
    char* lsb = (char*)ls;
    int y = blockIdx.x, b = blockIdx.y;
    int tid = threadIdx.x, lane = tid & 63, wid = tid >> 6;

    f32x4 acc[8][4];
    for (int pg = 0; pg < 8; ++pg)
        for (int u = 0; u < 4; ++u) acc[pg][u] = (f32x4){0.f, 0.f, 0.f, 0.f};

    for (int r = 0; r < 3; ++r) {
        int grow = y - 1 + r;
        if (grow < 0) grow = -grow;
        else if (grow > 127) grow = 254 - grow;
        __syncthreads();
        const short* src = out1 + ((size_t)b * 16384 + grow * 128) * 128;
        for (int it = 0; it < 9; ++it) {
            int gid = tid + it * 256;
            if (gid < 130 * 16) {
                int L = gid >> 4, gr = gid & 15;
                int gcol = L - 1;
                if (gcol < 0) gcol = -gcol;
                else if (gcol > 127) gcol = 254 - gcol;
                bf16x8 v = *(const bf16x8*)(src + (size_t)gcol * 128 + gr * 8);
                *(bf16x8*)(lsb + L * 256 + ((gr ^ (L & 15)) << 4)) = v;
            }
        }
        __syncthreads();
        for (int s = 0; s < 3; ++s)
            for (int kc = 0; kc < 4; ++kc) {
                int co = kc * 32 + (lane >> 4) * 8;
                bf16x8 afr[8], bfr[4];
                for (int pg = 0; pg < 8; ++pg) {
                    int L = pg * 16 + (lane & 15) + s;
                    afr[pg] = *(const bf16x8*)(lsb + swz(L, co));
                }
                const short* wb = wp2 + (r * 3 + s) * 256 * 128;
                for (int u = 0; u < 4; ++u) {
                    int o = (wid * 4 + u) * 16 + (lane & 15);
                    bfr[u] = *(const bf16x8*)(wb + o * 128 + co);
                }
                for (int pg = 0; pg < 8; ++pg)
                    for (int u = 0; u < 4; ++u)
                        acc[pg][u] = MFMA(afr[pg], bfr[u], acc[pg][u]);
            }
    }
    for (int u = 0; u < 4; ++u) {
        int o = (wid * 4 + u) * 16 + (lane & 15);
        float bias = b2[o];
        float* dst = outp + ((size_t)b * 256 + o) * 16384 + y * 128;
        for (int pg = 0; pg < 8; ++pg) {
            float4 v;
            v.x = acc[pg][u][0] + bias;
            v.y = acc[pg][u][1] + bias;
            v.z = acc[pg][u][2] + bias;
            v.w = acc[pg][u][3] + bias;
            *(float4*)(dst + pg * 16 + (lane >> 4) * 4) = v;
        }
    }
}

extern "C" void kernel_launch(void* const* d_in, const int* in_sizes, int n_in,
                              void* d_out, int out_size, void* d_ws, size_t ws_size,
                              hipStream_t stream) {
    const float* cont = (const float*)d_in[0];
    const float* styl = (const float*)d_in[1];
    const float* W1 = (const float*)d_in[2];
    const float* b1 = (const float*)d_in[3];
    const float* W2 = (const float*)d_in[4];
    const float* b2 = (const float*)d_in[5];
    float* outp = (float*)d_out;
    char* ws = (char*)d_ws;

    float* G       = (float*)(ws + 0x0);        // 16*128*128 f32 = 1 MiB
    float* S       = (float*)(ws + 0x100000);   // 2*8*128 f32
    short* Tb      = (short*)(ws + 0x110000);   // 8*128*128 bf16
    float* Vv      = (float*)(ws + 0x150000);   // 8*128 f32
    short* wp1     = (short*)(ws + 0x160000);   // 9*128*128 bf16
    short* wp2     = (short*)(ws + 0x1A8000);   // 9*256*128 bf16
    short* colored = (short*)(ws + 0x400000);   // 8*65536*128 bf16 = 128 MiB NHWC
    float* part    = (float*)(ws + 0x400000);   // 512*16K f32 = 32 MiB (aliases colored)
    short* out1    = (short*)(ws + 0x8400000);  // 8*16384*128 bf16 = 32 MiB NHWC

    hipMemsetAsync(S, 0, 0x2000, stream);       // zero S accumulator only
    k_prep<<<1728, 256, 0, stream>>>(W1, W2, wp1, wp2);
    // styl FIRST, cont SECOND: Infinity Cache retains cont for k_transform
    k_gram<<<256, 256, 0, stream>>>(styl, 1, part, S);
    k_gram<<<256, 256, 0, stream>>>(cont, 0, part, S);
    k_gsum<<<1024, 256, 0, stream>>>(part, G);
    k_solve<<<8, 256, 0, stream>>>(G, S, Tb, Vv);
    k_transform<<<4096, 256, 0, stream>>>(cont, Tb, Vv, colored);
    k_conv1<<<dim3(128, 8), 256, 0, stream>>>(colored, wp1, b1, out1);
    k_conv2<<<dim3(128, 8), 256, 0, stream>>>(out1, wp2, b2, outp);
}